// Round 1
// baseline (329.996 us; speedup 1.0000x reference)
//
#include <hip/hip_runtime.h>

// SpatialTransformer: out[i,j,k,c] = trilinear(vol[0], (i,j,k) + trf[0,i,j,k,:])
// vol: [2,160,192,224,2] f32 (batch 0 only), trf: [2,160,192,224,3] f32 (batch 0)
// out: [160,192,224,2] f32
//
// R1: 135us flat-index.  R2: 131us pair-merged gathers.  R4: 1D grid, 3D tiles.
// R5: 4 voxels/thread (2x ILP on the trf->gather chain), nontemporal trf/out
//     (protect vol in L2), bijective XCD swizzle for vol L2 locality.

constexpr int D0 = 160, D1 = 192, D2 = 224;
constexpr int TI = 8, TJ = 8, TK = 16;          // tile: 8i x 8j x 16k voxels
constexpr int GT_I = D0 / TI;   // 20
constexpr int GT_J = D1 / TJ;   // 24
constexpr int GT_K = D2 / TK;   // 14
constexpr int NBLOCKS = GT_I * GT_J * GT_K;     // 6720 (divisible by 8 XCDs)
constexpr int CPX = NBLOCKS / 8;                // 840 blocks per XCD chunk

// 16B vector with only-8B alignment guarantee (vol pair gathers)
typedef float float4u __attribute__((ext_vector_type(4), aligned(8)));
// 16B vector, fully aligned (trf loads / out stores)
typedef float vfloat4 __attribute__((ext_vector_type(4)));

__device__ __forceinline__ float2 sample_one(const float2* __restrict__ vol2,
                                             float fi, float fj, float fk,
                                             float s0, float s1, float s2)
{
    float l0 = fminf(fmaxf(fi + s0, 0.0f), (float)(D0 - 1));
    float l1 = fminf(fmaxf(fj + s1, 0.0f), (float)(D1 - 1));
    float l2 = fminf(fmaxf(fk + s2, 0.0f), (float)(D2 - 1));

    float f0 = floorf(l0), f1 = floorf(l1), f2 = floorf(l2);
    float g0 = fminf(f0 + 1.0f, (float)(D0 - 1));
    float g1 = fminf(f1 + 1.0f, (float)(D1 - 1));
    float g2 = fminf(f2 + 1.0f, (float)(D2 - 1));

    float w0a = g0 - l0, w1a = g1 - l1, w2a = g2 - l2;
    float w0b = 1.0f - w0a, w1b = 1.0f - w1a, w2b = 1.0f - w2a;

    int i0 = (int)f0, j0 = (int)f1, k0 = (int)f2;
    int i1 = (int)g0, j1 = (int)g1;
    // When k0==D2-1, w2a==0, so reading pair (D2-2, D2-1) is still exact.
    int kb = min(k0, D2 - 2);

    int r0 = i0 * (D1 * D2), r1 = i1 * (D1 * D2);
    int c0 = j0 * D2,        c1 = j1 * D2;

    float4u q00 = *(const float4u*)(vol2 + (r0 + c0 + kb));
    float4u q01 = *(const float4u*)(vol2 + (r0 + c1 + kb));
    float4u q10 = *(const float4u*)(vol2 + (r1 + c0 + kb));
    float4u q11 = *(const float4u*)(vol2 + (r1 + c1 + kb));

    float v00x = w2a * q00.x + w2b * q00.z, v00y = w2a * q00.y + w2b * q00.w;
    float v01x = w2a * q01.x + w2b * q01.z, v01y = w2a * q01.y + w2b * q01.w;
    float v10x = w2a * q10.x + w2b * q10.z, v10y = w2a * q10.y + w2b * q10.w;
    float v11x = w2a * q11.x + w2b * q11.z, v11y = w2a * q11.y + w2b * q11.w;

    float waa = w0a * w1a, wab = w0a * w1b, wba = w0b * w1a, wbb = w0b * w1b;
    float2 r;
    r.x = waa * v00x + wab * v01x + wba * v10x + wbb * v11x;
    r.y = waa * v00y + wab * v01y + wba * v10y + wbb * v11y;
    return r;
}

__global__ __launch_bounds__(256) void st_trilinear8_kernel(
    const float* __restrict__ vol,   // [D0,D1,D2,2]
    const float* __restrict__ trf,   // [D0,D1,D2,3]
    vfloat4* __restrict__ out)       // voxel-pairs
{
    // bijective XCD swizzle: hardware round-robins blockIdx across 8 XCDs;
    // map so each XCD gets a contiguous chunk of spatial tiles (vol L2 reuse).
    int b  = blockIdx.x;
    int sw = (b & 7) * CPX + (b >> 3);

    int tk = sw % GT_K;
    int tb = sw / GT_K;
    int tj = tb % GT_J;
    int ti = tb / GT_J;

    int tid = threadIdx.x;
    int kq  = tid & 3;           // 4 quads of 4 voxels -> 16 k per tile
    int j_l = (tid >> 2) & 7;    // 0..7
    int i_l = tid >> 5;          // 0..7

    int i = ti * TI + i_l;
    int j = tj * TJ + j_l;
    int k = tk * TK + kq * 4;

    int v0 = (i * D1 + j) * D2 + k;   // first voxel (multiple of 4)
    int u  = v0 >> 1;                 // voxel-pair index (even)

    // trf for 4 voxels = 12 floats = 3 aligned float4 (48B-aligned base)
    const float* tp = trf + 3 * (size_t)v0;
    vfloat4 T0 = __builtin_nontemporal_load((const vfloat4*)tp);
    vfloat4 T1 = __builtin_nontemporal_load((const vfloat4*)(tp + 4));
    vfloat4 T2 = __builtin_nontemporal_load((const vfloat4*)(tp + 8));

    const float2* vol2 = (const float2*)vol;
    float fi = (float)i, fj = (float)j, fk = (float)k;

    float2 A = sample_one(vol2, fi, fj, fk,        T0.x, T0.y, T0.z);
    float2 B = sample_one(vol2, fi, fj, fk + 1.0f, T0.w, T1.x, T1.y);
    float2 C = sample_one(vol2, fi, fj, fk + 2.0f, T1.z, T1.w, T2.x);
    float2 D = sample_one(vol2, fi, fj, fk + 3.0f, T2.y, T2.z, T2.w);

    vfloat4 o0 = { A.x, A.y, B.x, B.y };
    vfloat4 o1 = { C.x, C.y, D.x, D.y };
    __builtin_nontemporal_store(o0, &out[u]);
    __builtin_nontemporal_store(o1, &out[u + 1]);
}

extern "C" void kernel_launch(void* const* d_in, const int* in_sizes, int n_in,
                              void* d_out, int out_size, void* d_ws, size_t ws_size,
                              hipStream_t stream) {
    const float* vol = (const float*)d_in[0];
    const float* trf = (const float*)d_in[1];
    vfloat4* out = (vfloat4*)d_out;

    st_trilinear8_kernel<<<NBLOCKS, 256, 0, stream>>>(vol, trf, out);
}

// Round 2
// 302.249 us; speedup vs baseline: 1.0918x; 1.0918x over previous
//
#include <hip/hip_runtime.h>

// SpatialTransformer: out[i,j,k,c] = trilinear(vol[0], (i,j,k) + trf[0,i,j,k,:])
// vol: [2,160,192,224,2] f32 (batch 0 only), trf: [2,160,192,224,3] f32 (batch 0)
// out: [160,192,224,2] f32
//
// R1 135us flat. R2 131us pair-merged. R5 105us 4vox/thread + NT + XCD swizzle:
//   hbm 21%, VALU 11% -> bound by scattered-gather VMEM request path.
// R6: stage tile+halo(4) of vol into LDS; all interp reads hit LDS.
//   Rare (|shift|>4, ~1% of waves) samples fall back to global path.

constexpr int D0 = 160, D1 = 192, D2 = 224;
constexpr int TI = 8, TJ = 16, TK = 16;          // output tile per block
constexpr int GT_I = D0 / TI;   // 20
constexpr int GT_J = D1 / TJ;   // 12
constexpr int GT_K = D2 / TK;   // 14
constexpr int NBLOCKS = GT_I * GT_J * GT_K;      // 3360 (divisible by 8 XCDs)
constexpr int CPX = NBLOCKS / 8;                 // 420

constexpr int HALO = 4;
constexpr int RI = TI + 2 * HALO;   // 16
constexpr int RJ = TJ + 2 * HALO;   // 24
constexpr int RK = TK + 2 * HALO;   // 24 (staged k extent)
constexpr int RKP = 25;             // padded k extent in LDS (bank spread)
constexpr int NTHREADS = 512;
// region floats4 per block: RI*RJ rows * (RK*2/4) = 16*24*12 = 4608 -> 9/thread
constexpr int STAGE_ITERS = (RI * RJ * (RK / 2)) / NTHREADS;  // 9

// 16B vector with only-8B alignment guarantee
typedef float float4u __attribute__((ext_vector_type(4), aligned(8)));
typedef float vfloat4 __attribute__((ext_vector_type(4)));

__device__ __forceinline__ float2 sample_one(const float2* __restrict__ vol2,
                                             const float2* lds,
                                             int bi, int bj, int bk,
                                             float fi, float fj, float fk,
                                             float s0, float s1, float s2)
{
    float l0 = fminf(fmaxf(fi + s0, 0.0f), (float)(D0 - 1));
    float l1 = fminf(fmaxf(fj + s1, 0.0f), (float)(D1 - 1));
    float l2 = fminf(fmaxf(fk + s2, 0.0f), (float)(D2 - 1));

    float f0 = floorf(l0), f1 = floorf(l1), f2 = floorf(l2);
    float g0 = fminf(f0 + 1.0f, (float)(D0 - 1));
    float g1 = fminf(f1 + 1.0f, (float)(D1 - 1));
    float g2 = fminf(f2 + 1.0f, (float)(D2 - 1));

    float w0a = g0 - l0, w1a = g1 - l1, w2a = g2 - l2;
    float w0b = 1.0f - w0a, w1b = 1.0f - w1a, w2b = 1.0f - w2a;

    int i0 = (int)f0, j0 = (int)f1, k0 = (int)f2;
    int i1 = (int)g0, j1 = (int)g1;
    // When k0==D2-1, w2a==0, so reading pair (D2-2, D2-1) is still exact.
    int kb = min(k0, D2 - 2);

    bool inr = (i0 >= bi) && (i1 <= bi + RI - 1) &&
               (j0 >= bj) && (j1 <= bj + RJ - 1) &&
               (kb >= bk) && (kb <= bk + RK - 2);

    float4u q00, q01, q10, q11;
    if (__builtin_expect(inr, 1)) {
        int rk = kb - bk;
        int a00 = ((i0 - bi) * RJ + (j0 - bj)) * RKP + rk;
        int a01 = ((i0 - bi) * RJ + (j1 - bj)) * RKP + rk;
        int a10 = ((i1 - bi) * RJ + (j0 - bj)) * RKP + rk;
        int a11 = ((i1 - bi) * RJ + (j1 - bj)) * RKP + rk;
        float2 p00a = lds[a00], p00b = lds[a00 + 1];
        float2 p01a = lds[a01], p01b = lds[a01 + 1];
        float2 p10a = lds[a10], p10b = lds[a10 + 1];
        float2 p11a = lds[a11], p11b = lds[a11 + 1];
        q00 = float4u{p00a.x, p00a.y, p00b.x, p00b.y};
        q01 = float4u{p01a.x, p01a.y, p01b.x, p01b.y};
        q10 = float4u{p10a.x, p10a.y, p10b.x, p10b.y};
        q11 = float4u{p11a.x, p11a.y, p11b.x, p11b.y};
    } else {
        int r0 = i0 * (D1 * D2), r1 = i1 * (D1 * D2);
        int c0 = j0 * D2,        c1 = j1 * D2;
        q00 = *(const float4u*)(vol2 + (r0 + c0 + kb));
        q01 = *(const float4u*)(vol2 + (r0 + c1 + kb));
        q10 = *(const float4u*)(vol2 + (r1 + c0 + kb));
        q11 = *(const float4u*)(vol2 + (r1 + c1 + kb));
    }

    float v00x = w2a * q00.x + w2b * q00.z, v00y = w2a * q00.y + w2b * q00.w;
    float v01x = w2a * q01.x + w2b * q01.z, v01y = w2a * q01.y + w2b * q01.w;
    float v10x = w2a * q10.x + w2b * q10.z, v10y = w2a * q10.y + w2b * q10.w;
    float v11x = w2a * q11.x + w2b * q11.z, v11y = w2a * q11.y + w2b * q11.w;

    float waa = w0a * w1a, wab = w0a * w1b, wba = w0b * w1a, wbb = w0b * w1b;
    float2 r;
    r.x = waa * v00x + wab * v01x + wba * v10x + wbb * v11x;
    r.y = waa * v00y + wab * v01y + wba * v10y + wbb * v11y;
    return r;
}

__global__ __launch_bounds__(NTHREADS) void st_lds_kernel(
    const float* __restrict__ vol,   // [D0,D1,D2,2]
    const float* __restrict__ trf,   // [D0,D1,D2,3]
    vfloat4* __restrict__ out)       // voxel-pairs
{
    __shared__ float2 lds[RI * RJ * RKP];   // 16*24*25*8 = 76.8 KB -> 2 blocks/CU

    // bijective XCD swizzle: contiguous tile chunks per XCD for vol L2 reuse
    int b  = blockIdx.x;
    int sw = (b & 7) * CPX + (b >> 3);
    int tk = sw % GT_K;
    int tb = sw / GT_K;
    int tj = tb % GT_J;
    int ti = tb / GT_J;

    // staged region base (always fully inside the volume; covers tile +/- HALO
    // after boundary clamping of sample coords)
    int bi = min(max(ti * TI - HALO, 0), D0 - RI);
    int bj = min(max(tj * TJ - HALO, 0), D1 - RJ);
    int bk = min(max(tk * TK - HALO, 0), D2 - RK);   // even -> rows 16B aligned

    int tid = threadIdx.x;

    // per-thread output voxels: 4 consecutive k
    int kq  = tid & 3;
    int j_l = (tid >> 2) & 15;
    int i_l = tid >> 6;
    int i = ti * TI + i_l;
    int j = tj * TJ + j_l;
    int k = tk * TK + kq * 4;
    int v0 = (i * D1 + j) * D2 + k;
    int u  = v0 >> 1;

    // issue trf loads first: HBM latency overlaps staging + barrier
    const float* tp = trf + 3 * (size_t)v0;
    vfloat4 T0 = __builtin_nontemporal_load((const vfloat4*)tp);
    vfloat4 T1 = __builtin_nontemporal_load((const vfloat4*)(tp + 4));
    vfloat4 T2 = __builtin_nontemporal_load((const vfloat4*)(tp + 8));

    // stage region [RI][RJ][RK] float2 -> LDS [RI][RJ][RKP]
    // each row = RK*8B = 192B = 12 float4, contiguous & 16B-aligned in global
    #pragma unroll
    for (int n = 0; n < STAGE_ITERS; ++n) {
        int f   = tid + NTHREADS * n;    // 0..4607
        int fir = f % 12;                // float4 within row
        int row = f / 12;
        int rj  = row % RJ;
        int ri  = row / RJ;
        const float* src = vol +
            ((size_t)((bi + ri) * D1 + (bj + rj)) * D2 + bk) * 2 + fir * 4;
        float4u v = *(const float4u*)src;
        int li = (ri * RJ + rj) * RKP + fir * 2;
        lds[li]     = make_float2(v.x, v.y);
        lds[li + 1] = make_float2(v.z, v.w);
    }

    __syncthreads();

    const float2* vol2 = (const float2*)vol;
    float fi = (float)i, fj = (float)j, fk = (float)k;

    float2 A = sample_one(vol2, lds, bi, bj, bk, fi, fj, fk,        T0.x, T0.y, T0.z);
    float2 B = sample_one(vol2, lds, bi, bj, bk, fi, fj, fk + 1.0f, T0.w, T1.x, T1.y);
    float2 C = sample_one(vol2, lds, bi, bj, bk, fi, fj, fk + 2.0f, T1.z, T1.w, T2.x);
    float2 D = sample_one(vol2, lds, bi, bj, bk, fi, fj, fk + 3.0f, T2.y, T2.z, T2.w);

    vfloat4 o0 = { A.x, A.y, B.x, B.y };
    vfloat4 o1 = { C.x, C.y, D.x, D.y };
    __builtin_nontemporal_store(o0, &out[u]);
    __builtin_nontemporal_store(o1, &out[u + 1]);
}

extern "C" void kernel_launch(void* const* d_in, const int* in_sizes, int n_in,
                              void* d_out, int out_size, void* d_ws, size_t ws_size,
                              hipStream_t stream) {
    const float* vol = (const float*)d_in[0];
    const float* trf = (const float*)d_in[1];
    vfloat4* out = (vfloat4*)d_out;

    st_lds_kernel<<<NBLOCKS, NTHREADS, 0, stream>>>(vol, trf, out);
}

// Round 3
// 294.893 us; speedup vs baseline: 1.1190x; 1.0249x over previous
//
#include <hip/hip_runtime.h>

// SpatialTransformer: out[i,j,k,c] = trilinear(vol[0], (i,j,k) + trf[0,i,j,k,:])
// vol: [2,160,192,224,2] f32 (batch 0 only), trf: [2,160,192,224,3] f32 (batch 0)
// out: [160,192,224,2] f32
//
// R1 135us flat. R2 131us pair-merged. R5 105us 4vox/thread + NT + XCD swizzle
//   (NT was a regression: inputs are L3-resident across iterations, NT forfeits
//   that). R6 ~78us: LDS tile+halo staging, all interp reads from LDS (still NT).
// R7: R6 minus ALL nontemporal hints -> trf/out served by L2/L3.

constexpr int D0 = 160, D1 = 192, D2 = 224;
constexpr int TI = 8, TJ = 16, TK = 16;          // output tile per block
constexpr int GT_I = D0 / TI;   // 20
constexpr int GT_J = D1 / TJ;   // 12
constexpr int GT_K = D2 / TK;   // 14
constexpr int NBLOCKS = GT_I * GT_J * GT_K;      // 3360 (divisible by 8 XCDs)
constexpr int CPX = NBLOCKS / 8;                 // 420

constexpr int HALO = 4;
constexpr int RI = TI + 2 * HALO;   // 16
constexpr int RJ = TJ + 2 * HALO;   // 24
constexpr int RK = TK + 2 * HALO;   // 24 (staged k extent)
constexpr int RKP = 25;             // padded k extent in LDS (bank spread)
constexpr int NTHREADS = 512;
// region float4s per block: RI*RJ rows * (RK*2/4) = 16*24*12 = 4608 -> 9/thread
constexpr int STAGE_ITERS = (RI * RJ * (RK / 2)) / NTHREADS;  // 9

// 16B vector with only-8B alignment guarantee
typedef float float4u __attribute__((ext_vector_type(4), aligned(8)));
typedef float vfloat4 __attribute__((ext_vector_type(4)));

__device__ __forceinline__ float2 sample_one(const float2* __restrict__ vol2,
                                             const float2* lds,
                                             int bi, int bj, int bk,
                                             float fi, float fj, float fk,
                                             float s0, float s1, float s2)
{
    float l0 = fminf(fmaxf(fi + s0, 0.0f), (float)(D0 - 1));
    float l1 = fminf(fmaxf(fj + s1, 0.0f), (float)(D1 - 1));
    float l2 = fminf(fmaxf(fk + s2, 0.0f), (float)(D2 - 1));

    float f0 = floorf(l0), f1 = floorf(l1), f2 = floorf(l2);
    float g0 = fminf(f0 + 1.0f, (float)(D0 - 1));
    float g1 = fminf(f1 + 1.0f, (float)(D1 - 1));
    float g2 = fminf(f2 + 1.0f, (float)(D2 - 1));

    float w0a = g0 - l0, w1a = g1 - l1, w2a = g2 - l2;
    float w0b = 1.0f - w0a, w1b = 1.0f - w1a, w2b = 1.0f - w2a;

    int i0 = (int)f0, j0 = (int)f1, k0 = (int)f2;
    int i1 = (int)g0, j1 = (int)g1;
    // When k0==D2-1, w2a==0, so reading pair (D2-2, D2-1) is still exact.
    int kb = min(k0, D2 - 2);

    bool inr = (i0 >= bi) && (i1 <= bi + RI - 1) &&
               (j0 >= bj) && (j1 <= bj + RJ - 1) &&
               (kb >= bk) && (kb <= bk + RK - 2);

    float4u q00, q01, q10, q11;
    if (__builtin_expect(inr, 1)) {
        int rk = kb - bk;
        int a00 = ((i0 - bi) * RJ + (j0 - bj)) * RKP + rk;
        int a01 = ((i0 - bi) * RJ + (j1 - bj)) * RKP + rk;
        int a10 = ((i1 - bi) * RJ + (j0 - bj)) * RKP + rk;
        int a11 = ((i1 - bi) * RJ + (j1 - bj)) * RKP + rk;
        float2 p00a = lds[a00], p00b = lds[a00 + 1];
        float2 p01a = lds[a01], p01b = lds[a01 + 1];
        float2 p10a = lds[a10], p10b = lds[a10 + 1];
        float2 p11a = lds[a11], p11b = lds[a11 + 1];
        q00 = float4u{p00a.x, p00a.y, p00b.x, p00b.y};
        q01 = float4u{p01a.x, p01a.y, p01b.x, p01b.y};
        q10 = float4u{p10a.x, p10a.y, p10b.x, p10b.y};
        q11 = float4u{p11a.x, p11a.y, p11b.x, p11b.y};
    } else {
        int r0 = i0 * (D1 * D2), r1 = i1 * (D1 * D2);
        int c0 = j0 * D2,        c1 = j1 * D2;
        q00 = *(const float4u*)(vol2 + (r0 + c0 + kb));
        q01 = *(const float4u*)(vol2 + (r0 + c1 + kb));
        q10 = *(const float4u*)(vol2 + (r1 + c0 + kb));
        q11 = *(const float4u*)(vol2 + (r1 + c1 + kb));
    }

    float v00x = w2a * q00.x + w2b * q00.z, v00y = w2a * q00.y + w2b * q00.w;
    float v01x = w2a * q01.x + w2b * q01.z, v01y = w2a * q01.y + w2b * q01.w;
    float v10x = w2a * q10.x + w2b * q10.z, v10y = w2a * q10.y + w2b * q10.w;
    float v11x = w2a * q11.x + w2b * q11.z, v11y = w2a * q11.y + w2b * q11.w;

    float waa = w0a * w1a, wab = w0a * w1b, wba = w0b * w1a, wbb = w0b * w1b;
    float2 r;
    r.x = waa * v00x + wab * v01x + wba * v10x + wbb * v11x;
    r.y = waa * v00y + wab * v01y + wba * v10y + wbb * v11y;
    return r;
}

__global__ __launch_bounds__(NTHREADS) void st_lds_kernel(
    const float* __restrict__ vol,   // [D0,D1,D2,2]
    const float* __restrict__ trf,   // [D0,D1,D2,3]
    vfloat4* __restrict__ out)       // voxel-pairs
{
    __shared__ float2 lds[RI * RJ * RKP];   // 16*24*25*8 = 76.8 KB -> 2 blocks/CU

    // bijective XCD swizzle: contiguous tile chunks per XCD for vol L2 reuse
    int b  = blockIdx.x;
    int sw = (b & 7) * CPX + (b >> 3);
    int tk = sw % GT_K;
    int tb = sw / GT_K;
    int tj = tb % GT_J;
    int ti = tb / GT_J;

    // staged region base (always fully inside the volume; covers tile +/- HALO
    // after boundary clamping of sample coords)
    int bi = min(max(ti * TI - HALO, 0), D0 - RI);
    int bj = min(max(tj * TJ - HALO, 0), D1 - RJ);
    int bk = min(max(tk * TK - HALO, 0), D2 - RK);   // even -> rows 16B aligned

    int tid = threadIdx.x;

    // per-thread output voxels: 4 consecutive k
    int kq  = tid & 3;
    int j_l = (tid >> 2) & 15;
    int i_l = tid >> 6;
    int i = ti * TI + i_l;
    int j = tj * TJ + j_l;
    int k = tk * TK + kq * 4;
    int v0 = (i * D1 + j) * D2 + k;
    int u  = v0 >> 1;

    // issue trf loads first: memory latency overlaps staging + barrier
    const float* tp = trf + 3 * (size_t)v0;
    vfloat4 T0 = *(const vfloat4*)tp;
    vfloat4 T1 = *(const vfloat4*)(tp + 4);
    vfloat4 T2 = *(const vfloat4*)(tp + 8);

    // stage region [RI][RJ][RK] float2 -> LDS [RI][RJ][RKP]
    // each row = RK*8B = 192B = 12 float4, contiguous & 16B-aligned in global
    #pragma unroll
    for (int n = 0; n < STAGE_ITERS; ++n) {
        int f   = tid + NTHREADS * n;    // 0..4607
        int fir = f % 12;                // float4 within row
        int row = f / 12;
        int rj  = row % RJ;
        int ri  = row / RJ;
        const float* src = vol +
            ((size_t)((bi + ri) * D1 + (bj + rj)) * D2 + bk) * 2 + fir * 4;
        float4u v = *(const float4u*)src;
        int li = (ri * RJ + rj) * RKP + fir * 2;
        lds[li]     = make_float2(v.x, v.y);
        lds[li + 1] = make_float2(v.z, v.w);
    }

    __syncthreads();

    const float2* vol2 = (const float2*)vol;
    float fi = (float)i, fj = (float)j, fk = (float)k;

    float2 A = sample_one(vol2, lds, bi, bj, bk, fi, fj, fk,        T0.x, T0.y, T0.z);
    float2 B = sample_one(vol2, lds, bi, bj, bk, fi, fj, fk + 1.0f, T0.w, T1.x, T1.y);
    float2 C = sample_one(vol2, lds, bi, bj, bk, fi, fj, fk + 2.0f, T1.z, T1.w, T2.x);
    float2 D = sample_one(vol2, lds, bi, bj, bk, fi, fj, fk + 3.0f, T2.y, T2.z, T2.w);

    vfloat4 o0 = { A.x, A.y, B.x, B.y };
    vfloat4 o1 = { C.x, C.y, D.x, D.y };
    out[u]     = o0;
    out[u + 1] = o1;
}

extern "C" void kernel_launch(void* const* d_in, const int* in_sizes, int n_in,
                              void* d_out, int out_size, void* d_ws, size_t ws_size,
                              hipStream_t stream) {
    const float* vol = (const float*)d_in[0];
    const float* trf = (const float*)d_in[1];
    vfloat4* out = (vfloat4*)d_out;

    st_lds_kernel<<<NBLOCKS, NTHREADS, 0, stream>>>(vol, trf, out);
}